// Round 1
// baseline (1616.740 us; speedup 1.0000x reference)
//
#include <hip/hip_runtime.h>
#include <math.h>

namespace {

constexpr int kB = 32;
constexpr int kN = 19;
constexpr int kT = 2048;
constexpr int kD = 128;

// Single-wave workgroups: 6 tiles x 10 lanes = 60 active lanes, 4 idle (6.7%).
// No cross-wave barriers exist -> __syncthreads() is just the per-wave waitcnt
// we need anyway; every wave is an independent pipeline. 16 waves/CU resident
// (VGPR cap 128 via launch_bounds(64,4); LDS 10,080 B would allow 16 too).
constexpr int TILES = 6;           // (b,t) tiles per single-wave block
constexpr int TPT   = 10;          // threads per tile: upper-tri of 4x4 grid of 5x5
constexpr int BDIM  = 64;          // ONE wave
constexpr int KC    = 16;          // k-chunk depth (floats per staging round)
constexpr int SROW  = kN * KC;     // stage tile stride = 304 floats
constexpr int CHUNK_F4 = TILES * kN * (KC / 4); // 456 float4 per chunk

constexpr int RPAD  = 21;          // odd G-row pitch -> conflict-light LDS
constexpr int TSTR  = 400;         // 19*21=399 -> 400

constexpr int NT    = kB * kT;                    // 65536 tiles total
constexpr int NGRID = (NT + TILES - 1) / TILES;   // 10923 blocks (last has 4 valid tiles)

constexpr float kTempInv = 10.0f;  // 1/TEMPERATURE
constexpr float kThresh  = 1e-4f;

__global__ __launch_bounds__(BDIM, 4)
void fused_graph_kernel(const float* __restrict__ feat, float* __restrict__ out)
{
    // Union: Phase A staging [6][19][16] floats (7,296 B) then reused as the
    // per-tile Gram/prob matrices [6][19 x pitch 21] (9,600 B) + sInv (480 B).
    __shared__ float smem[TILES * TSTR + TILES * 20];   // 2,520 floats = 10,080 B

    const int lane = threadIdx.x;
    int tl = lane / TPT;               // tile-local index 0..5 (6 for idle lanes)
    const int sub = lane - tl * TPT;   // 0..9 -> (bi,bj), bi<=bj
    const bool laneValid = (tl < TILES);
    if (!laneValid) tl = TILES - 1;    // lanes 60..63 shadow tile 5; writes guarded

    const int bi    = (sub >= 4) + (sub >= 7) + (sub >= 9);
    const int start = bi * 4 - (bi * (bi - 1)) / 2;
    const int bj    = bi + (sub - start);

    const int gt0 = blockIdx.x * TILES;                    // global tile base = b*T + t
    const int vT  = (NT - gt0 < TILES) ? (NT - gt0) : TILES; // valid tiles (tail block)

    // clamped row indices for my 5x5 block (row 19 -> 18; garbage acc never used)
    int ar[5], bc[5];
#pragma unroll
    for (int r = 0; r < 5; ++r) { ar[r] = bi * 5 + r; if (ar[r] > kN - 1) ar[r] = kN - 1; }
#pragma unroll
    for (int c = 0; c < 5; ++c) { bc[c] = bj * 5 + c; if (bc[c] > kN - 1) bc[c] = kN - 1; }

    float acc[5][5];
#pragma unroll
    for (int r = 0; r < 5; ++r)
#pragma unroll
        for (int c = 0; c < 5; ++c) acc[r][c] = 0.f;

    // ============ Phase A: coalesced k-chunked staging + 5x5 register-blocked Gram ============
    for (int kc = 0; kc < kD; kc += KC) {
        // stage 6 tiles x 19 rows x 16 floats. q -> (d4,t,n): 4 consecutive
        // lanes cover one 64 B contiguous run. Tiles may cross the b boundary
        // (6 does not divide 2048), so the base is recomputed from g exactly.
        for (int q = lane; q < CHUNK_F4; q += BDIM) {
            const int d4 = q & 3;
            const int r  = q >> 2;          // 0..113
            const int t  = r % TILES;
            const int n  = r / TILES;
            int g = gt0 + t;
            if (g > NT - 1) g = NT - 1;     // tail block: clamp (duplicate reads, safe)
            // feat element (b,n,t,d) at ((b*kN+n)*kT + tt)*kD + d
            const size_t flat = (((size_t)(g >> 11) * kN + n) << 11) + (size_t)(g & (kT - 1));
            const float4 v = *(const float4*)(feat + (flat << 7) + kc + (d4 << 2));
            *(float4*)(&smem[t * SROW + n * KC + d4 * 4]) = v;
        }
        __syncthreads();   // single-wave workgroup: compiles to the needed waitcnt only

        const float* base = &smem[tl * SROW];
#pragma unroll
        for (int s0 = 0; s0 < 4; ++s0) {
            const int s = (s0 + sub) & 3;   // stagger to spread LDS banks
            float4 ra[5], cb[5];
#pragma unroll
            for (int r = 0; r < 5; ++r)
                ra[r] = *(const float4*)(base + ar[r] * KC + s * 4);
            if (bi == bj) {
#pragma unroll
                for (int c = 0; c < 5; ++c) cb[c] = ra[c];
            } else {
#pragma unroll
                for (int c = 0; c < 5; ++c)
                    cb[c] = *(const float4*)(base + bc[c] * KC + s * 4);
            }
#pragma unroll
            for (int r = 0; r < 5; ++r)
#pragma unroll
                for (int c = 0; c < 5; ++c) {
                    acc[r][c] = fmaf(ra[r].x, cb[c].x, acc[r][c]);
                    acc[r][c] = fmaf(ra[r].y, cb[c].y, acc[r][c]);
                    acc[r][c] = fmaf(ra[r].z, cb[c].z, acc[r][c]);
                    acc[r][c] = fmaf(ra[r].w, cb[c].w, acc[r][c]);
                }
        }
        __syncthreads();
    }

    // ============ Phase A2: scatter Gram into LDS (overwrites staging) with mirror ============
    {
        float* g = &smem[tl * TSTR];
#pragma unroll
        for (int r = 0; r < 5; ++r) {
            const int i = bi * 5 + r;
#pragma unroll
            for (int c = 0; c < 5; ++c) {
                const int j = bj * 5 + c;
                if (laneValid && i < kN && j < kN) {
                    g[i * RPAD + j] = acc[r][c];
                    if (i != j) g[j * RPAD + i] = acc[r][c];
                }
            }
        }
    }
    __syncthreads();

    // ============ Phase B1: inverse norms from Gram diagonal ============
    float* sInv = &smem[TILES * TSTR];
    for (int q = lane; q < TILES * kN; q += BDIM) {
        const int tt = q / kN;
        const int i  = q - tt * kN;
        const float nrm = sqrtf(smem[tt * TSTR + i * RPAD + i]);
        sInv[tt * 20 + i] = 1.0f / fmaxf(nrm, 1e-12f);
    }
    __syncthreads();

    // ============ Phase B2: per-row softmax + exact top-3 + threshold (in place) ============
    for (int q = lane; q < TILES * kN; q += BDIM) {
        const int tt = q / kN;
        const int i  = q - tt * kN;
        float* row = &smem[tt * TSTR + i * RPAD];
        const float* invp = &sInv[tt * 20];
        const float si = invp[i] * kTempInv;

        float l[kN];
        float m = -3.0e38f;
#pragma unroll
        for (int j = 0; j < kN; ++j) {
            const float g = row[j] * si * invp[j];
            l[j] = g;
            m = fmaxf(m, g);
        }
        float ssum = 0.f;
#pragma unroll
        for (int j = 0; j < kN; ++j) {
            const float e = __expf(l[j] - m);
            l[j] = e;
            ssum += e;
        }
        const float rs = 1.0f / ssum;
#pragma unroll
        for (int j = 0; j < kN; ++j) l[j] *= rs;

        // top-3 with lax.top_k tie semantics (strict > keeps lowest index on ties)
        int k1 = 0; float v1 = -1.f;
#pragma unroll
        for (int j = 0; j < kN; ++j) if (l[j] > v1) { v1 = l[j]; k1 = j; }
        int k2 = -1; float v2 = -1.f;
#pragma unroll
        for (int j = 0; j < kN; ++j) if (j != k1 && l[j] > v2) { v2 = l[j]; k2 = j; }
        int k3 = -1; float v3 = -1.f;
#pragma unroll
        for (int j = 0; j < kN; ++j) if (j != k1 && j != k2 && l[j] > v3) { v3 = l[j]; k3 = j; }

#pragma unroll
        for (int j = 0; j < kN; ++j) {
            const float p = l[j];
            const bool keep = (j == k1 || j == k2 || j == k3) && (p > kThresh);
            row[j] = keep ? p : 0.f;
        }
    }
    __syncthreads();

    // ============ Phase C: symmetrize + contiguous coalesced store ============
    float* ob = out + (size_t)gt0 * (kN * kN);
    const int qMax = vT * (kN * kN);   // tail block stores only valid tiles
    for (int q = lane; q < qMax; q += BDIM) {
        const int tt = q / (kN * kN);
        const int r  = q - tt * (kN * kN);
        const int i  = r / kN;
        const int j  = r - i * kN;
        const float v = 0.5f * (smem[tt * TSTR + i * RPAD + j] +
                                smem[tt * TSTR + j * RPAD + i]);
        ob[q] = v;   // contiguous span per block
    }
}

} // namespace

extern "C" void kernel_launch(void* const* d_in, const int* in_sizes, int n_in,
                              void* d_out, int out_size, void* d_ws, size_t ws_size,
                              hipStream_t stream)
{
    const float* feat = (const float*)d_in[0];
    float* out = (float*)d_out;
    dim3 grid(NGRID);    // 10923 single-wave blocks
    dim3 block(BDIM);    // 64 threads = 1 wave
    hipLaunchKernelGGL(fused_graph_kernel, grid, block, 0, stream, feat, out);
}

// Round 2
// 977.501 us; speedup vs baseline: 1.6540x; 1.6540x over previous
//
#include <hip/hip_runtime.h>
#include <math.h>

namespace {

constexpr int kB = 32;
constexpr int kN = 19;
constexpr int kT = 2048;
constexpr int kD = 128;

// Single-wave workgroups: 6 tiles x 10 lanes = 60 active lanes, 4 idle (6.7%).
// No cross-wave barriers exist -> __syncthreads() is just the per-wave waitcnt
// we need anyway; every wave is an independent pipeline.
constexpr int TILES = 6;           // (b,t) tiles per single-wave block
constexpr int TPT   = 10;          // threads per tile: upper-tri of 4x4 grid of 5x5
constexpr int BDIM  = 64;          // ONE wave
constexpr int KC    = 16;          // k-chunk depth (floats per staging round)
constexpr int SROW  = kN * KC;     // stage tile stride = 304 floats
constexpr int CHUNK_F4 = TILES * kN * (KC / 4); // 456 float4 per chunk

constexpr int RPAD  = 21;          // odd G-row pitch -> conflict-light LDS
constexpr int TSTR  = 400;         // 19*21=399 -> 400

constexpr int NT    = kB * kT;                    // 65536 tiles total
constexpr int NGRID = (NT + TILES - 1) / TILES;   // 10923 blocks (last has 4 valid tiles)

constexpr float kTempInv = 10.0f;  // 1/TEMPERATURE
constexpr float kThresh  = 1e-4f;

// (64,2): VGPR cap 256 -> compiler lands ~120-130, NO SPILL. Round 1's (64,4)
// forced the 64-reg tier and produced ~1.9 GB of scratch writes (WRITE_SIZE
// 2.01 GB vs 92 MB output) — the whole dispatch became spill traffic.
// At ~120 VGPR: 4 waves/SIMD (16 waves/CU); LDS 10,080 B x 16 = 161,280 B
// fits the 163,840 B pool -> 16 independent single-wave pipelines per CU.
__global__ __launch_bounds__(BDIM, 2)
void fused_graph_kernel(const float* __restrict__ feat, float* __restrict__ out)
{
    // Union: Phase A staging [6][19][16] floats (7,296 B) then reused as the
    // per-tile Gram/prob matrices [6][19 x pitch 21] (9,600 B) + sInv (480 B).
    __shared__ float smem[TILES * TSTR + TILES * 20];   // 2,520 floats = 10,080 B

    const int lane = threadIdx.x;
    int tl = lane / TPT;               // tile-local index 0..5 (6 for idle lanes)
    const int sub = lane - tl * TPT;   // 0..9 -> (bi,bj), bi<=bj
    const bool laneValid = (tl < TILES);
    if (!laneValid) tl = TILES - 1;    // lanes 60..63 shadow tile 5; writes guarded

    const int bi    = (sub >= 4) + (sub >= 7) + (sub >= 9);
    const int start = bi * 4 - (bi * (bi - 1)) / 2;
    const int bj    = bi + (sub - start);

    const int gt0 = blockIdx.x * TILES;                    // global tile base = b*T + t
    const int vT  = (NT - gt0 < TILES) ? (NT - gt0) : TILES; // valid tiles (tail block)

    // clamped row indices for my 5x5 block (row 19 -> 18; garbage acc never used)
    int ar[5], bc[5];
#pragma unroll
    for (int r = 0; r < 5; ++r) { ar[r] = bi * 5 + r; if (ar[r] > kN - 1) ar[r] = kN - 1; }
#pragma unroll
    for (int c = 0; c < 5; ++c) { bc[c] = bj * 5 + c; if (bc[c] > kN - 1) bc[c] = kN - 1; }

    float acc[5][5];
#pragma unroll
    for (int r = 0; r < 5; ++r)
#pragma unroll
        for (int c = 0; c < 5; ++c) acc[r][c] = 0.f;

    // ============ Phase A: coalesced k-chunked staging + 5x5 register-blocked Gram ============
    for (int kc = 0; kc < kD; kc += KC) {
        // stage 6 tiles x 19 rows x 16 floats. q -> (d4,t,n): 4 consecutive
        // lanes cover one 64 B contiguous run. Tiles may cross the b boundary
        // (6 does not divide 2048), so the base is recomputed from g exactly.
        for (int q = lane; q < CHUNK_F4; q += BDIM) {
            const int d4 = q & 3;
            const int r  = q >> 2;          // 0..113
            const int t  = r % TILES;
            const int n  = r / TILES;
            int g = gt0 + t;
            if (g > NT - 1) g = NT - 1;     // tail block: clamp (duplicate reads, safe)
            // feat element (b,n,t,d) at ((b*kN+n)*kT + tt)*kD + d
            const size_t flat = (((size_t)(g >> 11) * kN + n) << 11) + (size_t)(g & (kT - 1));
            const float4 v = *(const float4*)(feat + (flat << 7) + kc + (d4 << 2));
            *(float4*)(&smem[t * SROW + n * KC + d4 * 4]) = v;
        }
        __syncthreads();   // single-wave workgroup: compiles to the needed waitcnt only

        const float* base = &smem[tl * SROW];
#pragma unroll
        for (int s0 = 0; s0 < 4; ++s0) {
            const int s = (s0 + sub) & 3;   // stagger to spread LDS banks
            float4 ra[5], cb[5];
#pragma unroll
            for (int r = 0; r < 5; ++r)
                ra[r] = *(const float4*)(base + ar[r] * KC + s * 4);
            if (bi == bj) {
#pragma unroll
                for (int c = 0; c < 5; ++c) cb[c] = ra[c];
            } else {
#pragma unroll
                for (int c = 0; c < 5; ++c)
                    cb[c] = *(const float4*)(base + bc[c] * KC + s * 4);
            }
#pragma unroll
            for (int r = 0; r < 5; ++r)
#pragma unroll
                for (int c = 0; c < 5; ++c) {
                    acc[r][c] = fmaf(ra[r].x, cb[c].x, acc[r][c]);
                    acc[r][c] = fmaf(ra[r].y, cb[c].y, acc[r][c]);
                    acc[r][c] = fmaf(ra[r].z, cb[c].z, acc[r][c]);
                    acc[r][c] = fmaf(ra[r].w, cb[c].w, acc[r][c]);
                }
        }
        __syncthreads();
    }

    // ============ Phase A2: scatter Gram into LDS (overwrites staging) with mirror ============
    {
        float* g = &smem[tl * TSTR];
#pragma unroll
        for (int r = 0; r < 5; ++r) {
            const int i = bi * 5 + r;
#pragma unroll
            for (int c = 0; c < 5; ++c) {
                const int j = bj * 5 + c;
                if (laneValid && i < kN && j < kN) {
                    g[i * RPAD + j] = acc[r][c];
                    if (i != j) g[j * RPAD + i] = acc[r][c];
                }
            }
        }
    }
    __syncthreads();

    // ============ Phase B1: inverse norms from Gram diagonal ============
    float* sInv = &smem[TILES * TSTR];
    for (int q = lane; q < TILES * kN; q += BDIM) {
        const int tt = q / kN;
        const int i  = q - tt * kN;
        const float nrm = sqrtf(smem[tt * TSTR + i * RPAD + i]);
        sInv[tt * 20 + i] = 1.0f / fmaxf(nrm, 1e-12f);
    }
    __syncthreads();

    // ============ Phase B2: per-row softmax + exact top-3 + threshold (in place) ============
    for (int q = lane; q < TILES * kN; q += BDIM) {
        const int tt = q / kN;
        const int i  = q - tt * kN;
        float* row = &smem[tt * TSTR + i * RPAD];
        const float* invp = &sInv[tt * 20];
        const float si = invp[i] * kTempInv;

        float l[kN];
        float m = -3.0e38f;
#pragma unroll
        for (int j = 0; j < kN; ++j) {
            const float g = row[j] * si * invp[j];
            l[j] = g;
            m = fmaxf(m, g);
        }
        float ssum = 0.f;
#pragma unroll
        for (int j = 0; j < kN; ++j) {
            const float e = __expf(l[j] - m);
            l[j] = e;
            ssum += e;
        }
        const float rs = 1.0f / ssum;
#pragma unroll
        for (int j = 0; j < kN; ++j) l[j] *= rs;

        // top-3 with lax.top_k tie semantics (strict > keeps lowest index on ties)
        int k1 = 0; float v1 = -1.f;
#pragma unroll
        for (int j = 0; j < kN; ++j) if (l[j] > v1) { v1 = l[j]; k1 = j; }
        int k2 = -1; float v2 = -1.f;
#pragma unroll
        for (int j = 0; j < kN; ++j) if (j != k1 && l[j] > v2) { v2 = l[j]; k2 = j; }
        int k3 = -1; float v3 = -1.f;
#pragma unroll
        for (int j = 0; j < kN; ++j) if (j != k1 && j != k2 && l[j] > v3) { v3 = l[j]; k3 = j; }

#pragma unroll
        for (int j = 0; j < kN; ++j) {
            const float p = l[j];
            const bool keep = (j == k1 || j == k2 || j == k3) && (p > kThresh);
            row[j] = keep ? p : 0.f;
        }
    }
    __syncthreads();

    // ============ Phase C: symmetrize + contiguous coalesced store ============
    float* ob = out + (size_t)gt0 * (kN * kN);
    const int qMax = vT * (kN * kN);   // tail block stores only valid tiles
    for (int q = lane; q < qMax; q += BDIM) {
        const int tt = q / (kN * kN);
        const int r  = q - tt * (kN * kN);
        const int i  = r / kN;
        const int j  = r - i * kN;
        const float v = 0.5f * (smem[tt * TSTR + i * RPAD + j] +
                                smem[tt * TSTR + j * RPAD + i]);
        ob[q] = v;   // contiguous span per block
    }
}

} // namespace

extern "C" void kernel_launch(void* const* d_in, const int* in_sizes, int n_in,
                              void* d_out, int out_size, void* d_ws, size_t ws_size,
                              hipStream_t stream)
{
    const float* feat = (const float*)d_in[0];
    float* out = (float*)d_out;
    dim3 grid(NGRID);    // 10923 single-wave blocks
    dim3 block(BDIM);    // 64 threads = 1 wave
    hipLaunchKernelGGL(fused_graph_kernel, grid, block, 0, stream, feat, out);
}